// Round 13
// baseline (195.148 us; speedup 1.0000x reference)
//
#include <hip/hip_runtime.h>
#include <hip/hip_bf16.h>

// Problem: B=2, LQ=2048, LK=4096, D_MODEL=512, NHEAD=8, D_HEAD=64
// Round 18 (= R17 resubmitted after infra failure): R11 base (177.8us).
// ONE lever, attn only: l-sum moved from the VALU (30-add dependent tree per
// tile) to the MFMA pipe via a ones-column B-fragment appended to PV --
// l[q] = P.1 accumulates in f32x16 alongside O. Removes the tree + final
// shfl; lpart written from the ql==0 lanes. Everything else identical to R11.

using bf16   = __hip_bfloat16;
using bf16x8 = __attribute__((ext_vector_type(8))) short;  // 8 bf16 = 4 VGPRs
using f32x4  = __attribute__((ext_vector_type(4))) float;
using f32x16 = __attribute__((ext_vector_type(16))) float;
using uint4v = __attribute__((ext_vector_type(4))) unsigned int;

#define MFMA16(a, b, c) __builtin_amdgcn_mfma_f32_16x16x32_bf16((a), (b), (c), 0, 0, 0)
#define MFMA32(a, b, c) __builtin_amdgcn_mfma_f32_32x32x16_bf16((a), (b), (c), 0, 0, 0)

__device__ __forceinline__ bf16x8 load8(const bf16* p) {
    return *reinterpret_cast<const bf16x8*>(p);
}
__device__ __forceinline__ unsigned short f2bf(float x) {
    bf16 h = __float2bfloat16(x);
    return *reinterpret_cast<unsigned short*>(&h);
}

// ---------------------------------------------------------------------------
// One fused prep kernel: q/kv -> bf16, 4 weight matrices -> bf16,
// gate+mask -> g2 (log2 domain). Exact grid: 7176 x 256.
// ---------------------------------------------------------------------------
__global__ void cvt_all(const float* __restrict__ q, const float* __restrict__ kv,
                        const float* __restrict__ Wq, const float* __restrict__ Wk,
                        const float* __restrict__ Wv, const float* __restrict__ Wo,
                        const float* __restrict__ gate, const int* __restrict__ mask,
                        bf16* __restrict__ qb, bf16* __restrict__ kvb,
                        bf16* __restrict__ Wqb, bf16* __restrict__ Wkb,
                        bf16* __restrict__ Wvb, bf16* __restrict__ Wob,
                        float* __restrict__ g2) {
    const int i = blockIdx.x * 256 + threadIdx.x;
    if (i < 1835008) {
        const float* src; bf16* dst; int j;
        if (i < 524288)       { src = q;  dst = qb;  j = i; }
        else if (i < 1572864) { src = kv; dst = kvb; j = i - 524288; }
        else {
            const int i2 = i - 1572864;
            const int t = i2 >> 16; j = i2 & 65535;
            src = (t == 0) ? Wq : (t == 1) ? Wk : (t == 2) ? Wv : Wo;
            dst = (t == 0) ? Wqb : (t == 1) ? Wkb : (t == 2) ? Wvb : Wob;
        }
        float4 v = reinterpret_cast<const float4*>(src)[j];
        ushort4 o;
        o.x = f2bf(v.x); o.y = f2bf(v.y); o.z = f2bf(v.z); o.w = f2bf(v.w);
        reinterpret_cast<ushort4*>(dst)[j] = o;
    } else {
        const int u = i - 1835008;                     // 0..2047
        float4 gv = reinterpret_cast<const float4*>(gate)[u];
        int4   mv = reinterpret_cast<const int4*>(mask)[u];
        float4 o;
        o.x = mv.x ? log2f(fmaxf(gv.x, 1e-6f)) : -1e30f;
        o.y = mv.y ? log2f(fmaxf(gv.y, 1e-6f)) : -1e30f;
        o.z = mv.z ? log2f(fmaxf(gv.z, 1e-6f)) : -1e30f;
        o.w = mv.w ? log2f(fmaxf(gv.w, 1e-6f)) : -1e30f;
        reinterpret_cast<float4*>(g2)[u] = o;
    }
}

// ---------------------------------------------------------------------------
// Projection body (R11): C = X @ W^T + bias. X:[M,512] bf16, W bf16
// row-major. K-loop register double-buffered. mode 0: fp32 row-major;
// mode 1: per-head bf16 (Q); mode 3/4: K/V fragment-major. bf16 modes stage
// the wave's 4KB output tile through LDS -> coalesced bf16x8 stores.
// ---------------------------------------------------------------------------
__device__ __forceinline__ void proj_body(const bf16* __restrict__ X,
                                          const bf16* __restrict__ W,
                                          const float* __restrict__ bias,
                                          void* __restrict__ Cout,
                                          int mode, int L, int mb, int nb,
                                          bf16* Ws) {
    const int tid  = threadIdx.x;
    const int wave = tid >> 6;
    const int lane = tid & 63;
    const int li   = lane & 15;
    const int quad = lane >> 4;
    const int n0   = nb * 64;
    const int m0   = mb * 128 + wave * 32;

    f32x4 zero = {0.f, 0.f, 0.f, 0.f};
    f32x4 acc[2][4];
    for (int mt = 0; mt < 2; ++mt)
        for (int t = 0; t < 4; ++t) acc[mt][t] = zero;

    const bf16* x0 = X + (size_t)(m0 + li) * 512;
    const bf16* x1 = X + (size_t)(m0 + 16 + li) * 512;

    for (int p = 0; p < 2; ++p) {
        __syncthreads();
        for (int i = 0; i < 8; ++i) {        // stage 64 x 256 W block
            const int c  = i * 256 + tid;
            const int cr = c >> 5;
            const int kc = (c & 31) * 8;
            *reinterpret_cast<bf16x8*>(&Ws[cr * 264 + kc]) =
                load8(W + (size_t)(n0 + cr) * 512 + p * 256 + kc);
        }
        __syncthreads();

        const bf16* xp0 = x0 + p * 256 + quad * 8;
        const bf16* xp1 = x1 + p * 256 + quad * 8;

        bf16x8 a0 = load8(xp0);
        bf16x8 a1 = load8(xp1);
        bf16x8 wr0 = load8(&Ws[(0 * 16 + li) * 264 + quad * 8]);
        bf16x8 wr1 = load8(&Ws[(1 * 16 + li) * 264 + quad * 8]);
        bf16x8 wr2 = load8(&Ws[(2 * 16 + li) * 264 + quad * 8]);
        bf16x8 wr3 = load8(&Ws[(3 * 16 + li) * 264 + quad * 8]);

        #pragma unroll
        for (int k0 = 0; k0 < 256; k0 += 32) {
            const int kn = (k0 < 224) ? k0 + 32 : k0;   // clamped prefetch
            bf16x8 a0n = load8(xp0 + kn);
            bf16x8 a1n = load8(xp1 + kn);
            bf16x8 wn0 = load8(&Ws[(0 * 16 + li) * 264 + kn + quad * 8]);
            bf16x8 wn1 = load8(&Ws[(1 * 16 + li) * 264 + kn + quad * 8]);
            bf16x8 wn2 = load8(&Ws[(2 * 16 + li) * 264 + kn + quad * 8]);
            bf16x8 wn3 = load8(&Ws[(3 * 16 + li) * 264 + kn + quad * 8]);

            acc[0][0] = MFMA16(a0, wr0, acc[0][0]);
            acc[1][0] = MFMA16(a1, wr0, acc[1][0]);
            acc[0][1] = MFMA16(a0, wr1, acc[0][1]);
            acc[1][1] = MFMA16(a1, wr1, acc[1][1]);
            acc[0][2] = MFMA16(a0, wr2, acc[0][2]);
            acc[1][2] = MFMA16(a1, wr2, acc[1][2]);
            acc[0][3] = MFMA16(a0, wr3, acc[0][3]);
            acc[1][3] = MFMA16(a1, wr3, acc[1][3]);

            a0 = a0n; a1 = a1n;
            wr0 = wn0; wr1 = wn1; wr2 = wn2; wr3 = wn3;
        }
    }

    if (mode == 0) {
        for (int t = 0; t < 4; ++t) {
            const int col = n0 + t * 16 + li;
            const float bcol = bias[col];
            for (int mt = 0; mt < 2; ++mt)
                for (int r = 0; r < 4; ++r) {
                    const int row = m0 + mt * 16 + quad * 4 + r;
                    ((float*)Cout)[(size_t)row * 512 + col] = acc[mt][t][r] + bcol;
                }
        }
    } else {
        __syncthreads();                       // Ws no longer needed as W tile
        bf16* slab = Ws + wave * 2048;         // wave's 4KB staging slice
        #pragma unroll
        for (int t = 0; t < 4; ++t) {
            const float bcol = bias[n0 + t * 16 + li];
            #pragma unroll
            for (int mt = 0; mt < 2; ++mt)
                #pragma unroll
                for (int r = 0; r < 4; ++r) {
                    const float v = acc[mt][t][r] + bcol;
                    int lidx;
                    if (mode == 1)
                        lidx = (mt * 16 + quad * 4 + r) * 64 + t * 16 + li;
                    else if (mode == 3)
                        lidx = t * 512 + (li >> 3) * 256 + (mt * 16 + quad * 4 + r) * 8 + (li & 7);
                    else  // mode 4
                        lidx = (t >> 1) * 1024 + mt * 512 + (quad >> 1) * 256
                             + ((t & 1) * 16 + li) * 8 + (quad & 1) * 4 + r;
                    slab[lidx] = __float2bfloat16(v);
                }
        }
        __syncthreads();
        const int bb2 = m0 / L;
        const int i0  = m0 - bb2 * L;
        const int hh  = n0 >> 6;
        const int bh  = bb2 * 8 + hh;
        bf16* base;
        if (mode == 1) base = (bf16*)Cout + ((size_t)bh * L + i0) * 64;
        else           base = (bf16*)Cout + (size_t)bh * L * 64 + (size_t)(i0 >> 5) * 2048;
        #pragma unroll
        for (int s = 0; s < 4; ++s)
            *reinterpret_cast<bf16x8*>(base + s * 512 + lane * 8) =
                load8(&slab[s * 512 + lane * 8]);
    }
}

// Fused Q/K/V projections: 1280 blocks, XCD-grouped swizzle.
__global__ void proj_qkv(const bf16* __restrict__ qb, const bf16* __restrict__ kvb,
                         const bf16* __restrict__ Wq, const float* __restrict__ bq,
                         const bf16* __restrict__ Wk, const float* __restrict__ bk,
                         const bf16* __restrict__ Wv, const float* __restrict__ bv,
                         bf16* __restrict__ qp, bf16* __restrict__ kf,
                         bf16* __restrict__ vf) {
    __shared__ alignas(16) bf16 Ws[64 * 264];
    const int l   = blockIdx.x;              // 0..1279
    const int w   = l & 63;
    const int myy = (l >> 6) * 8 + (w & 7);  // 0..159
    const int nb  = w >> 3;                  // 0..7
    if (myy < 32)      proj_body(qb,  Wq, bq, qp, 1, 2048, myy,      nb, Ws);
    else if (myy < 96) proj_body(kvb, Wk, bk, kf, 3, 4096, myy - 32, nb, Ws);
    else               proj_body(kvb, Wv, bv, vf, 4, 4096, myy - 96, nb, Ws);
}

// Output projection: 256 blocks, same swizzle, fp32 out.
__global__ void proj_o(const bf16* __restrict__ op, const bf16* __restrict__ Wo,
                       const float* __restrict__ bo, float* __restrict__ out) {
    __shared__ alignas(16) bf16 Ws[64 * 264];
    const int l = blockIdx.x;                // 0..255
    const int w = l & 63;
    proj_body(op, Wo, bo, out, 0, 1, (l >> 6) * 8 + (w & 7), w >> 3, Ws);
}

// ---------------------------------------------------------------------------
// Barrier-free K-split flash attention, swapped QK^T, no LDS. SP=4.
// 512 blocks x 4 waves; wave owns 64 q-rows (2 sub-tiles). XCD-grouped
// swizzle; K, V, gate all double-buffered one tile ahead.
// l-sum computed on the MFMA pipe: ones-column B-fragment appended to PV.
// ---------------------------------------------------------------------------
template<int SP>
__global__ __launch_bounds__(256, 2)
void attn_kernel(const bf16* __restrict__ qp, const bf16* __restrict__ kf,
                 const bf16* __restrict__ vf, const float* __restrict__ g2,
                 float* __restrict__ Opart, float* __restrict__ lpart) {
    constexpr int NT    = 128 / SP;          // 32-key tiles per split
    constexpr int SLICE = 262144 / SP;       // elements per (bh,sp) K or V slice
    const int tid  = threadIdx.x;
    const int wave = tid >> 6;
    const int lane = tid & 63;
    const int ql   = lane & 31;
    const int hi   = lane >> 5;

    const int id = blockIdx.x;               // 0..128*SP-1
    const int qt = (id >> 3) & 7;
    const int gg = ((id >> 6) << 3) | (id & 7);   // bh*SP + sp
    const int bh = gg / SP;
    const int sp = gg % SP;
    const int b  = bh >> 3;
    const int q0 = qt * 256 + wave * 64;

    // Q B-fragments: bq[sub][ds]: lane holds Q[q0+sub*32+ql][ds*16 + hi*8 + j]
    bf16x8 bq[2][4];
    const bf16* qbp = qp + ((size_t)bh * 2048 + q0 + ql) * 64 + hi * 8;
    #pragma unroll
    for (int sub = 0; sub < 2; ++sub)
        #pragma unroll
        for (int ds = 0; ds < 4; ++ds)
            bq[sub][ds] = load8(qbp + sub * 2048 + ds * 16);

    // ones-column B-fragment for the l-sum MFMA: B[k][n] = (n == 0).
    // B n-index = lane&31 (same mapping as PV's V operand), so lanes with
    // ql==0 hold 1.0 in every k-slot; j-permutation-immune.
    const unsigned o1 = (ql == 0) ? 0x3F803F80u : 0u;
    uint4v uo = {o1, o1, o1, o1};
    const bf16x8 bones = __builtin_bit_cast(bf16x8, uo);

    f32x16 od[2][2];
    f32x16 ol[2];
    #pragma unroll
    for (int sub = 0; sub < 2; ++sub) {
        #pragma unroll
        for (int t = 0; t < 2; ++t)
            #pragma unroll
            for (int r = 0; r < 16; ++r) od[sub][t][r] = 0.f;
        #pragma unroll
        for (int r = 0; r < 16; ++r) ol[sub][r] = 0.f;
    }

    const bf16* kbase = kf + (size_t)bh * 262144 + (size_t)sp * SLICE + lane * 8;
    const bf16* vbase = vf + (size_t)bh * 262144 + (size_t)sp * SLICE + lane * 8;
    const float* gbase = g2 + (size_t)b * 4096 + sp * (4096 / SP) + hi * 4;

    const float SC = 0.18033688011112042f;   // log2(e) / 8

    // tile-0 preload: K, V, gate
    bf16x8 ka0 = load8(kbase);
    bf16x8 ka1 = load8(kbase + 512);
    bf16x8 ka2 = load8(kbase + 1024);
    bf16x8 ka3 = load8(kbase + 1536);
    bf16x8 va0 = load8(vbase);
    bf16x8 va1 = load8(vbase + 512);
    bf16x8 va2 = load8(vbase + 1024);
    bf16x8 va3 = load8(vbase + 1536);
    f32x4 ga0 = *(const f32x4*)(gbase);
    f32x4 ga1 = *(const f32x4*)(gbase + 8);
    f32x4 ga2 = *(const f32x4*)(gbase + 16);
    f32x4 ga3 = *(const f32x4*)(gbase + 24);

    for (int kt = 0; kt < NT; ++kt) {
        // issue next-tile prefetch FIRST: K, V, gate (clamped on last iter)
        const int ktn = kt < NT - 1 ? kt + 1 : NT - 1;
        const bf16* kp_n = kbase + (size_t)ktn * 2048;
        bf16x8 kn0 = load8(kp_n);
        bf16x8 kn1 = load8(kp_n + 512);
        bf16x8 kn2 = load8(kp_n + 1024);
        bf16x8 kn3 = load8(kp_n + 1536);
        const bf16* vp_n = vbase + (size_t)ktn * 2048;
        bf16x8 vn0 = load8(vp_n);
        bf16x8 vn1 = load8(vp_n + 512);
        bf16x8 vn2 = load8(vp_n + 1024);
        bf16x8 vn3 = load8(vp_n + 1536);
        const float* gp_n = gbase + ktn * 32;
        f32x4 gn0 = *(const f32x4*)(gp_n);
        f32x4 gn1 = *(const f32x4*)(gp_n + 8);
        f32x4 gn2 = *(const f32x4*)(gp_n + 16);
        f32x4 gn3 = *(const f32x4*)(gp_n + 24);

        // QK^T for both sub-tiles (registers only)
        f32x16 s0, s1;
        #pragma unroll
        for (int r = 0; r < 16; ++r) { s0[r] = 0.f; s1[r] = 0.f; }
        __builtin_amdgcn_s_setprio(1);
        s0 = MFMA32(ka0, bq[0][0], s0);
        s0 = MFMA32(ka1, bq[0][1], s0);
        s0 = MFMA32(ka2, bq[0][2], s0);
        s0 = MFMA32(ka3, bq[0][3], s0);
        s1 = MFMA32(ka0, bq[1][0], s1);
        s1 = MFMA32(ka1, bq[1][1], s1);
        s1 = MFMA32(ka2, bq[1][2], s1);
        s1 = MFMA32(ka3, bq[1][3], s1);
        __builtin_amdgcn_s_setprio(0);

        // in-register softmax (no-max): P = exp2(S*log2e/8 + log2gate).
        // No l-tree here -- l rides the PV MFMA via bones.
        bf16x8 pa00, pa01, pa10, pa11;
        auto softmax = [&](const f32x16& sacc, bf16x8& plo, bf16x8& phi) {
            float p[16];
            #pragma unroll
            for (int r = 0; r < 16; ++r) {
                const float gl = (r < 4) ? ga0[r & 3] : (r < 8) ? ga1[r & 3]
                               : (r < 12) ? ga2[r & 3] : ga3[r & 3];
                p[r] = __builtin_amdgcn_exp2f(fmaf(sacc[r], SC, gl));
            }
            unsigned w[8];
            #pragma unroll
            for (int i = 0; i < 8; ++i)
                asm("v_cvt_pk_bf16_f32 %0, %1, %2"
                    : "=v"(w[i]) : "v"(p[2 * i]), "v"(p[2 * i + 1]));
            asm("v_permlane32_swap_b32 %0, %1" : "+v"(w[0]), "+v"(w[2]));
            asm("v_permlane32_swap_b32 %0, %1" : "+v"(w[1]), "+v"(w[3]));
            asm("v_permlane32_swap_b32 %0, %1" : "+v"(w[4]), "+v"(w[6]));
            asm("v_permlane32_swap_b32 %0, %1" : "+v"(w[5]), "+v"(w[7]));
            uint4v u0 = {w[0], w[1], w[2], w[3]};
            uint4v u1 = {w[4], w[5], w[6], w[7]};
            plo = __builtin_bit_cast(bf16x8, u0);
            phi = __builtin_bit_cast(bf16x8, u1);
        };
        softmax(s0, pa00, pa01);
        softmax(s1, pa10, pa11);

        // O += P @ V; l += P @ 1 (ones-column, MFMA pipe)
        __builtin_amdgcn_s_setprio(1);
        od[0][0] = MFMA32(pa00, va0, od[0][0]);
        od[0][0] = MFMA32(pa01, va1, od[0][0]);
        od[0][1] = MFMA32(pa00, va2, od[0][1]);
        od[0][1] = MFMA32(pa01, va3, od[0][1]);
        od[1][0] = MFMA32(pa10, va0, od[1][0]);
        od[1][0] = MFMA32(pa11, va1, od[1][0]);
        od[1][1] = MFMA32(pa10, va2, od[1][1]);
        od[1][1] = MFMA32(pa11, va3, od[1][1]);
        ol[0] = MFMA32(pa00, bones, ol[0]);
        ol[0] = MFMA32(pa01, bones, ol[0]);
        ol[1] = MFMA32(pa10, bones, ol[1]);
        ol[1] = MFMA32(pa11, bones, ol[1]);
        __builtin_amdgcn_s_setprio(0);

        ka0 = kn0; ka1 = kn1; ka2 = kn2; ka3 = kn3;
        va0 = vn0; va1 = vn1; va2 = vn2; va3 = vn3;
        ga0 = gn0; ga1 = gn1; ga2 = gn2; ga3 = gn3;
    }

    // write fp32 partial O: Opart[(bh*2048 + q)*SP + sp]*64 + d
    float* ob = Opart + ((size_t)(bh * 2048 + q0) * SP + sp) * 64;
    #pragma unroll
    for (int sub = 0; sub < 2; ++sub)
        #pragma unroll
        for (int t = 0; t < 2; ++t)
            #pragma unroll
            for (int r = 0; r < 16; ++r) {
                const int qq = sub * 32 + (r & 3) + 8 * (r >> 2) + hi * 4;
                ob[(size_t)qq * (64 * SP) + t * 32 + ql] = od[sub][t][r];
            }

    // l lives at D[q][0]: held by the ql==0 lanes (lane 0: hi=0 rows,
    // lane 32: hi=1 rows), 16 rows per sub each.
    if (ql == 0) {
        #pragma unroll
        for (int sub = 0; sub < 2; ++sub)
            #pragma unroll
            for (int r = 0; r < 16; ++r) {
                const int qq = sub * 32 + (r & 3) + 8 * (r >> 2) + hi * 4;
                lpart[((size_t)(bh * 2048 + q0 + qq)) * SP + sp] = ol[sub][r];
            }
    }
}

// ---------------------------------------------------------------------------
// Combine SP K-split partials (plain sums; no max weights needed).
// ---------------------------------------------------------------------------
template<int SP>
__global__ void attn_combine(const float* __restrict__ Opart,
                             const float* __restrict__ lpart,
                             bf16* __restrict__ op) {
    const int gidx = blockIdx.x * 256 + threadIdx.x;  // 0..131071
    const int row  = gidx >> 2;                        // bh*2048 + q
    const int c0   = (gidx & 3) * 16;

    float acc[16];
    #pragma unroll
    for (int j = 0; j < 16; ++j) acc[j] = 0.f;
    float L = 0.f;
    #pragma unroll
    for (int s = 0; s < SP; ++s) {
        const float* src = Opart + ((size_t)row * SP + s) * 64 + c0;
        const float4 v0 = reinterpret_cast<const float4*>(src)[0];
        const float4 v1 = reinterpret_cast<const float4*>(src)[1];
        const float4 v2 = reinterpret_cast<const float4*>(src)[2];
        const float4 v3 = reinterpret_cast<const float4*>(src)[3];
        acc[0] += v0.x; acc[1] += v0.y; acc[2]  += v0.z; acc[3]  += v0.w;
        acc[4] += v1.x; acc[5] += v1.y; acc[6]  += v1.z; acc[7]  += v1.w;
        acc[8] += v2.x; acc[9] += v2.y; acc[10] += v2.z; acc[11] += v2.w;
        acc[12] += v3.x; acc[13] += v3.y; acc[14] += v3.z; acc[15] += v3.w;
        L += lpart[(size_t)row * SP + s];
    }
    const float invL = 1.0f / L;

    const int bh = row >> 11;
    const int q  = row & 2047;
    const int bb = bh >> 3;
    const int hh = bh & 7;
    bf16* dst = op + ((size_t)bb * 2048 + q) * 512 + hh * 64 + c0;
    bf16x8 r0, r1;
    #pragma unroll
    for (int j = 0; j < 8; ++j) {
        r0[j] = f2bf(acc[j] * invL);
        r1[j] = f2bf(acc[8 + j] * invL);
    }
    *reinterpret_cast<bf16x8*>(dst)     = r0;
    *reinterpret_cast<bf16x8*>(dst + 8) = r1;
}

// ---------------------------------------------------------------------------
extern "C" void kernel_launch(void* const* d_in, const int* in_sizes, int n_in,
                              void* d_out, int out_size, void* d_ws, size_t ws_size,
                              hipStream_t stream) {
    const float* q    = (const float*)d_in[0];
    const float* kv   = (const float*)d_in[1];
    const float* gate = (const float*)d_in[2];
    const int*   mask = (const int*)d_in[3];
    const float* Wq = (const float*)d_in[4];  const float* bq = (const float*)d_in[5];
    const float* Wk = (const float*)d_in[6];  const float* bk = (const float*)d_in[7];
    const float* Wv = (const float*)d_in[8];  const float* bv = (const float*)d_in[9];
    const float* Wo = (const float*)d_in[10]; const float* bo = (const float*)d_in[11];
    float* out = (float*)d_out;

    char* ws = (char*)d_ws;
    float* g2  = (float*)ws;
    bf16* Wqb  = (bf16*)(ws + (1u  << 20));
    bf16* Wkb  = (bf16*)(ws + (1u  << 20) + (512u << 10));
    bf16* Wvb  = (bf16*)(ws + (2u  << 20));
    bf16* Wob  = (bf16*)(ws + (2u  << 20) + (512u << 10));
    bf16* qb   = (bf16*)(ws + (3u  << 20));
    bf16* kvb  = (bf16*)(ws + (7u  << 20));
    bf16* qp   = (bf16*)(ws + (15u << 20));
    bf16* kf   = (bf16*)(ws + (19u << 20));
    bf16* vf   = (bf16*)(ws + (27u << 20));
    bf16* op   = (bf16*)(ws + (35u << 20));
    float* Opart = (float*)(ws + (39u << 20));
    float* lpart = (float*)(ws + (71u << 20));

    cvt_all<<<7176, 256, 0, stream>>>(q, kv, Wq, Wk, Wv, Wo, gate, mask,
                                      qb, kvb, Wqb, Wkb, Wvb, Wob, g2);

    proj_qkv<<<1280, 256, 0, stream>>>(qb, kvb, Wqb, bq, Wkb, bk,
                                       Wvb, bv, qp, kf, vf);

    attn_kernel<4><<<512, 256, 0, stream>>>(qp, kf, vf, g2, Opart, lpart);
    attn_combine<4><<<512, 256, 0, stream>>>(Opart, lpart, op);

    proj_o<<<256, 256, 0, stream>>>(op, Wob, bo, out);
}

// Round 14
// 177.494 us; speedup vs baseline: 1.0995x; 1.0995x over previous
//
#include <hip/hip_runtime.h>
#include <hip/hip_bf16.h>

// Problem: B=2, LQ=2048, LK=4096, D_MODEL=512, NHEAD=8, D_HEAD=64
// FINAL (round 19) = R10/R11 best-known configuration (177.7us), locked in
// after R13's l-via-MFMA regression (51->67us) confirmed attn is
// dependency-chain-bound at 2 waves/SIMD (unified-RF residency cap).
// Structure: cvt_all streaming bf16 prep; LDS-staged projections with XCD
// swizzle + register-dbuf k-loop + LDS epilogue; barrier-free SP=4 attn
// (swapped QK^T, in-register no-max softmax, K/V/gate dbuf); combine; proj_o.

using bf16   = __hip_bfloat16;
using bf16x8 = __attribute__((ext_vector_type(8))) short;  // 8 bf16 = 4 VGPRs
using f32x4  = __attribute__((ext_vector_type(4))) float;
using f32x16 = __attribute__((ext_vector_type(16))) float;
using uint4v = __attribute__((ext_vector_type(4))) unsigned int;

#define MFMA16(a, b, c) __builtin_amdgcn_mfma_f32_16x16x32_bf16((a), (b), (c), 0, 0, 0)
#define MFMA32(a, b, c) __builtin_amdgcn_mfma_f32_32x32x16_bf16((a), (b), (c), 0, 0, 0)

__device__ __forceinline__ bf16x8 load8(const bf16* p) {
    return *reinterpret_cast<const bf16x8*>(p);
}
__device__ __forceinline__ unsigned short f2bf(float x) {
    bf16 h = __float2bfloat16(x);
    return *reinterpret_cast<unsigned short*>(&h);
}

// ---------------------------------------------------------------------------
// One fused prep kernel: q/kv -> bf16, 4 weight matrices -> bf16,
// gate+mask -> g2 (log2 domain). Exact grid: 7176 x 256.
// ---------------------------------------------------------------------------
__global__ void cvt_all(const float* __restrict__ q, const float* __restrict__ kv,
                        const float* __restrict__ Wq, const float* __restrict__ Wk,
                        const float* __restrict__ Wv, const float* __restrict__ Wo,
                        const float* __restrict__ gate, const int* __restrict__ mask,
                        bf16* __restrict__ qb, bf16* __restrict__ kvb,
                        bf16* __restrict__ Wqb, bf16* __restrict__ Wkb,
                        bf16* __restrict__ Wvb, bf16* __restrict__ Wob,
                        float* __restrict__ g2) {
    const int i = blockIdx.x * 256 + threadIdx.x;
    if (i < 1835008) {
        const float* src; bf16* dst; int j;
        if (i < 524288)       { src = q;  dst = qb;  j = i; }
        else if (i < 1572864) { src = kv; dst = kvb; j = i - 524288; }
        else {
            const int i2 = i - 1572864;
            const int t = i2 >> 16; j = i2 & 65535;
            src = (t == 0) ? Wq : (t == 1) ? Wk : (t == 2) ? Wv : Wo;
            dst = (t == 0) ? Wqb : (t == 1) ? Wkb : (t == 2) ? Wvb : Wob;
        }
        float4 v = reinterpret_cast<const float4*>(src)[j];
        ushort4 o;
        o.x = f2bf(v.x); o.y = f2bf(v.y); o.z = f2bf(v.z); o.w = f2bf(v.w);
        reinterpret_cast<ushort4*>(dst)[j] = o;
    } else {
        const int u = i - 1835008;                     // 0..2047
        float4 gv = reinterpret_cast<const float4*>(gate)[u];
        int4   mv = reinterpret_cast<const int4*>(mask)[u];
        float4 o;
        o.x = mv.x ? log2f(fmaxf(gv.x, 1e-6f)) : -1e30f;
        o.y = mv.y ? log2f(fmaxf(gv.y, 1e-6f)) : -1e30f;
        o.z = mv.z ? log2f(fmaxf(gv.z, 1e-6f)) : -1e30f;
        o.w = mv.w ? log2f(fmaxf(gv.w, 1e-6f)) : -1e30f;
        reinterpret_cast<float4*>(g2)[u] = o;
    }
}

// ---------------------------------------------------------------------------
// Projection body: C = X @ W^T + bias. X:[M,512] bf16, W bf16 row-major.
// K-loop register double-buffered. mode 0: fp32 row-major; mode 1: per-head
// bf16 (Q); mode 3/4: K/V fragment-major. bf16 modes stage the wave's 4KB
// output tile through LDS -> coalesced bf16x8 stores.
// ---------------------------------------------------------------------------
__device__ __forceinline__ void proj_body(const bf16* __restrict__ X,
                                          const bf16* __restrict__ W,
                                          const float* __restrict__ bias,
                                          void* __restrict__ Cout,
                                          int mode, int L, int mb, int nb,
                                          bf16* Ws) {
    const int tid  = threadIdx.x;
    const int wave = tid >> 6;
    const int lane = tid & 63;
    const int li   = lane & 15;
    const int quad = lane >> 4;
    const int n0   = nb * 64;
    const int m0   = mb * 128 + wave * 32;

    f32x4 zero = {0.f, 0.f, 0.f, 0.f};
    f32x4 acc[2][4];
    for (int mt = 0; mt < 2; ++mt)
        for (int t = 0; t < 4; ++t) acc[mt][t] = zero;

    const bf16* x0 = X + (size_t)(m0 + li) * 512;
    const bf16* x1 = X + (size_t)(m0 + 16 + li) * 512;

    for (int p = 0; p < 2; ++p) {
        __syncthreads();
        for (int i = 0; i < 8; ++i) {        // stage 64 x 256 W block
            const int c  = i * 256 + tid;
            const int cr = c >> 5;
            const int kc = (c & 31) * 8;
            *reinterpret_cast<bf16x8*>(&Ws[cr * 264 + kc]) =
                load8(W + (size_t)(n0 + cr) * 512 + p * 256 + kc);
        }
        __syncthreads();

        const bf16* xp0 = x0 + p * 256 + quad * 8;
        const bf16* xp1 = x1 + p * 256 + quad * 8;

        bf16x8 a0 = load8(xp0);
        bf16x8 a1 = load8(xp1);
        bf16x8 wr0 = load8(&Ws[(0 * 16 + li) * 264 + quad * 8]);
        bf16x8 wr1 = load8(&Ws[(1 * 16 + li) * 264 + quad * 8]);
        bf16x8 wr2 = load8(&Ws[(2 * 16 + li) * 264 + quad * 8]);
        bf16x8 wr3 = load8(&Ws[(3 * 16 + li) * 264 + quad * 8]);

        #pragma unroll
        for (int k0 = 0; k0 < 256; k0 += 32) {
            const int kn = (k0 < 224) ? k0 + 32 : k0;   // clamped prefetch
            bf16x8 a0n = load8(xp0 + kn);
            bf16x8 a1n = load8(xp1 + kn);
            bf16x8 wn0 = load8(&Ws[(0 * 16 + li) * 264 + kn + quad * 8]);
            bf16x8 wn1 = load8(&Ws[(1 * 16 + li) * 264 + kn + quad * 8]);
            bf16x8 wn2 = load8(&Ws[(2 * 16 + li) * 264 + kn + quad * 8]);
            bf16x8 wn3 = load8(&Ws[(3 * 16 + li) * 264 + kn + quad * 8]);

            acc[0][0] = MFMA16(a0, wr0, acc[0][0]);
            acc[1][0] = MFMA16(a1, wr0, acc[1][0]);
            acc[0][1] = MFMA16(a0, wr1, acc[0][1]);
            acc[1][1] = MFMA16(a1, wr1, acc[1][1]);
            acc[0][2] = MFMA16(a0, wr2, acc[0][2]);
            acc[1][2] = MFMA16(a1, wr2, acc[1][2]);
            acc[0][3] = MFMA16(a0, wr3, acc[0][3]);
            acc[1][3] = MFMA16(a1, wr3, acc[1][3]);

            a0 = a0n; a1 = a1n;
            wr0 = wn0; wr1 = wn1; wr2 = wn2; wr3 = wn3;
        }
    }

    if (mode == 0) {
        for (int t = 0; t < 4; ++t) {
            const int col = n0 + t * 16 + li;
            const float bcol = bias[col];
            for (int mt = 0; mt < 2; ++mt)
                for (int r = 0; r < 4; ++r) {
                    const int row = m0 + mt * 16 + quad * 4 + r;
                    ((float*)Cout)[(size_t)row * 512 + col] = acc[mt][t][r] + bcol;
                }
        }
    } else {
        __syncthreads();                       // Ws no longer needed as W tile
        bf16* slab = Ws + wave * 2048;         // wave's 4KB staging slice
        #pragma unroll
        for (int t = 0; t < 4; ++t) {
            const float bcol = bias[n0 + t * 16 + li];
            #pragma unroll
            for (int mt = 0; mt < 2; ++mt)
                #pragma unroll
                for (int r = 0; r < 4; ++r) {
                    const float v = acc[mt][t][r] + bcol;
                    int lidx;
                    if (mode == 1)
                        lidx = (mt * 16 + quad * 4 + r) * 64 + t * 16 + li;
                    else if (mode == 3)
                        lidx = t * 512 + (li >> 3) * 256 + (mt * 16 + quad * 4 + r) * 8 + (li & 7);
                    else  // mode 4
                        lidx = (t >> 1) * 1024 + mt * 512 + (quad >> 1) * 256
                             + ((t & 1) * 16 + li) * 8 + (quad & 1) * 4 + r;
                    slab[lidx] = __float2bfloat16(v);
                }
        }
        __syncthreads();
        const int bb2 = m0 / L;
        const int i0  = m0 - bb2 * L;
        const int hh  = n0 >> 6;
        const int bh  = bb2 * 8 + hh;
        bf16* base;
        if (mode == 1) base = (bf16*)Cout + ((size_t)bh * L + i0) * 64;
        else           base = (bf16*)Cout + (size_t)bh * L * 64 + (size_t)(i0 >> 5) * 2048;
        #pragma unroll
        for (int s = 0; s < 4; ++s)
            *reinterpret_cast<bf16x8*>(base + s * 512 + lane * 8) =
                load8(&slab[s * 512 + lane * 8]);
    }
}

// Fused Q/K/V projections: 1280 blocks, XCD-grouped swizzle.
__global__ void proj_qkv(const bf16* __restrict__ qb, const bf16* __restrict__ kvb,
                         const bf16* __restrict__ Wq, const float* __restrict__ bq,
                         const bf16* __restrict__ Wk, const float* __restrict__ bk,
                         const bf16* __restrict__ Wv, const float* __restrict__ bv,
                         bf16* __restrict__ qp, bf16* __restrict__ kf,
                         bf16* __restrict__ vf) {
    __shared__ alignas(16) bf16 Ws[64 * 264];
    const int l   = blockIdx.x;              // 0..1279
    const int w   = l & 63;
    const int myy = (l >> 6) * 8 + (w & 7);  // 0..159
    const int nb  = w >> 3;                  // 0..7
    if (myy < 32)      proj_body(qb,  Wq, bq, qp, 1, 2048, myy,      nb, Ws);
    else if (myy < 96) proj_body(kvb, Wk, bk, kf, 3, 4096, myy - 32, nb, Ws);
    else               proj_body(kvb, Wv, bv, vf, 4, 4096, myy - 96, nb, Ws);
}

// Output projection: 256 blocks, same swizzle, fp32 out.
__global__ void proj_o(const bf16* __restrict__ op, const bf16* __restrict__ Wo,
                       const float* __restrict__ bo, float* __restrict__ out) {
    __shared__ alignas(16) bf16 Ws[64 * 264];
    const int l = blockIdx.x;                // 0..255
    const int w = l & 63;
    proj_body(op, Wo, bo, out, 0, 1, (l >> 6) * 8 + (w & 7), w >> 3, Ws);
}

// ---------------------------------------------------------------------------
// Barrier-free K-split flash attention, swapped QK^T, no LDS. SP=4.
// 512 blocks x 4 waves; wave owns 64 q-rows (2 sub-tiles). XCD-grouped
// swizzle; K, V, gate all double-buffered one tile ahead.
// ---------------------------------------------------------------------------
template<int SP>
__global__ __launch_bounds__(256, 2)
void attn_kernel(const bf16* __restrict__ qp, const bf16* __restrict__ kf,
                 const bf16* __restrict__ vf, const float* __restrict__ g2,
                 float* __restrict__ Opart, float* __restrict__ lpart) {
    constexpr int NT    = 128 / SP;          // 32-key tiles per split
    constexpr int SLICE = 262144 / SP;       // elements per (bh,sp) K or V slice
    const int tid  = threadIdx.x;
    const int wave = tid >> 6;
    const int lane = tid & 63;
    const int ql   = lane & 31;
    const int hi   = lane >> 5;

    const int id = blockIdx.x;               // 0..128*SP-1
    const int qt = (id >> 3) & 7;
    const int gg = ((id >> 6) << 3) | (id & 7);   // bh*SP + sp
    const int bh = gg / SP;
    const int sp = gg % SP;
    const int b  = bh >> 3;
    const int q0 = qt * 256 + wave * 64;

    // Q B-fragments: bq[sub][ds]: lane holds Q[q0+sub*32+ql][ds*16 + hi*8 + j]
    bf16x8 bq[2][4];
    const bf16* qbp = qp + ((size_t)bh * 2048 + q0 + ql) * 64 + hi * 8;
    #pragma unroll
    for (int sub = 0; sub < 2; ++sub)
        #pragma unroll
        for (int ds = 0; ds < 4; ++ds)
            bq[sub][ds] = load8(qbp + sub * 2048 + ds * 16);

    f32x16 od[2][2];
    #pragma unroll
    for (int sub = 0; sub < 2; ++sub)
        #pragma unroll
        for (int t = 0; t < 2; ++t)
            #pragma unroll
            for (int r = 0; r < 16; ++r) od[sub][t][r] = 0.f;
    float lsum[2] = {0.f, 0.f};

    const bf16* kbase = kf + (size_t)bh * 262144 + (size_t)sp * SLICE + lane * 8;
    const bf16* vbase = vf + (size_t)bh * 262144 + (size_t)sp * SLICE + lane * 8;
    const float* gbase = g2 + (size_t)b * 4096 + sp * (4096 / SP) + hi * 4;

    const float SC = 0.18033688011112042f;   // log2(e) / 8

    // tile-0 preload: K, V, gate
    bf16x8 ka0 = load8(kbase);
    bf16x8 ka1 = load8(kbase + 512);
    bf16x8 ka2 = load8(kbase + 1024);
    bf16x8 ka3 = load8(kbase + 1536);
    bf16x8 va0 = load8(vbase);
    bf16x8 va1 = load8(vbase + 512);
    bf16x8 va2 = load8(vbase + 1024);
    bf16x8 va3 = load8(vbase + 1536);
    f32x4 ga0 = *(const f32x4*)(gbase);
    f32x4 ga1 = *(const f32x4*)(gbase + 8);
    f32x4 ga2 = *(const f32x4*)(gbase + 16);
    f32x4 ga3 = *(const f32x4*)(gbase + 24);

    for (int kt = 0; kt < NT; ++kt) {
        // issue next-tile prefetch FIRST: K, V, gate (clamped on last iter)
        const int ktn = kt < NT - 1 ? kt + 1 : NT - 1;
        const bf16* kp_n = kbase + (size_t)ktn * 2048;
        bf16x8 kn0 = load8(kp_n);
        bf16x8 kn1 = load8(kp_n + 512);
        bf16x8 kn2 = load8(kp_n + 1024);
        bf16x8 kn3 = load8(kp_n + 1536);
        const bf16* vp_n = vbase + (size_t)ktn * 2048;
        bf16x8 vn0 = load8(vp_n);
        bf16x8 vn1 = load8(vp_n + 512);
        bf16x8 vn2 = load8(vp_n + 1024);
        bf16x8 vn3 = load8(vp_n + 1536);
        const float* gp_n = gbase + ktn * 32;
        f32x4 gn0 = *(const f32x4*)(gp_n);
        f32x4 gn1 = *(const f32x4*)(gp_n + 8);
        f32x4 gn2 = *(const f32x4*)(gp_n + 16);
        f32x4 gn3 = *(const f32x4*)(gp_n + 24);

        // QK^T for both sub-tiles (registers only)
        f32x16 s0, s1;
        #pragma unroll
        for (int r = 0; r < 16; ++r) { s0[r] = 0.f; s1[r] = 0.f; }
        __builtin_amdgcn_s_setprio(1);
        s0 = MFMA32(ka0, bq[0][0], s0);
        s0 = MFMA32(ka1, bq[0][1], s0);
        s0 = MFMA32(ka2, bq[0][2], s0);
        s0 = MFMA32(ka3, bq[0][3], s0);
        s1 = MFMA32(ka0, bq[1][0], s1);
        s1 = MFMA32(ka1, bq[1][1], s1);
        s1 = MFMA32(ka2, bq[1][2], s1);
        s1 = MFMA32(ka3, bq[1][3], s1);
        __builtin_amdgcn_s_setprio(0);

        // in-register softmax (no-max): P = exp2(S*log2e/8 + log2gate)
        bf16x8 pa00, pa01, pa10, pa11;
        auto softmax = [&](const f32x16& sacc, float& lacc, bf16x8& plo, bf16x8& phi) {
            float p[16];
            #pragma unroll
            for (int r = 0; r < 16; ++r) {
                const float gl = (r < 4) ? ga0[r & 3] : (r < 8) ? ga1[r & 3]
                               : (r < 12) ? ga2[r & 3] : ga3[r & 3];
                p[r] = __builtin_amdgcn_exp2f(fmaf(sacc[r], SC, gl));
            }
            unsigned w[8];
            #pragma unroll
            for (int i = 0; i < 8; ++i)
                asm("v_cvt_pk_bf16_f32 %0, %1, %2"
                    : "=v"(w[i]) : "v"(p[2 * i]), "v"(p[2 * i + 1]));
            #pragma unroll
            for (int st = 1; st < 16; st <<= 1)
                #pragma unroll
                for (int r = 0; r < 16; r += 2 * st) p[r] += p[r + st];
            lacc += p[0];
            asm("v_permlane32_swap_b32 %0, %1" : "+v"(w[0]), "+v"(w[2]));
            asm("v_permlane32_swap_b32 %0, %1" : "+v"(w[1]), "+v"(w[3]));
            asm("v_permlane32_swap_b32 %0, %1" : "+v"(w[4]), "+v"(w[6]));
            asm("v_permlane32_swap_b32 %0, %1" : "+v"(w[5]), "+v"(w[7]));
            uint4v u0 = {w[0], w[1], w[2], w[3]};
            uint4v u1 = {w[4], w[5], w[6], w[7]};
            plo = __builtin_bit_cast(bf16x8, u0);
            phi = __builtin_bit_cast(bf16x8, u1);
        };
        softmax(s0, lsum[0], pa00, pa01);
        softmax(s1, lsum[1], pa10, pa11);

        // O += P @ V (V already in registers -> no memory dependency)
        __builtin_amdgcn_s_setprio(1);
        od[0][0] = MFMA32(pa00, va0, od[0][0]);
        od[0][0] = MFMA32(pa01, va1, od[0][0]);
        od[0][1] = MFMA32(pa00, va2, od[0][1]);
        od[0][1] = MFMA32(pa01, va3, od[0][1]);
        od[1][0] = MFMA32(pa10, va0, od[1][0]);
        od[1][0] = MFMA32(pa11, va1, od[1][0]);
        od[1][1] = MFMA32(pa10, va2, od[1][1]);
        od[1][1] = MFMA32(pa11, va3, od[1][1]);
        __builtin_amdgcn_s_setprio(0);

        ka0 = kn0; ka1 = kn1; ka2 = kn2; ka3 = kn3;
        va0 = vn0; va1 = vn1; va2 = vn2; va3 = vn3;
        ga0 = gn0; ga1 = gn1; ga2 = gn2; ga3 = gn3;
    }

    float l0 = lsum[0] + __shfl_xor(lsum[0], 32);
    float l1 = lsum[1] + __shfl_xor(lsum[1], 32);

    // write fp32 partial O: Opart[(bh*2048 + q)*SP + sp]*64 + d
    float* ob = Opart + ((size_t)(bh * 2048 + q0) * SP + sp) * 64;
    #pragma unroll
    for (int sub = 0; sub < 2; ++sub)
        #pragma unroll
        for (int t = 0; t < 2; ++t)
            #pragma unroll
            for (int r = 0; r < 16; ++r) {
                const int qq = sub * 32 + (r & 3) + 8 * (r >> 2) + hi * 4;
                ob[(size_t)qq * (64 * SP) + t * 32 + ql] = od[sub][t][r];
            }
    if (lane < 32) {
        lpart[((size_t)(bh * 2048 + q0 + lane)) * SP + sp]      = l0;
        lpart[((size_t)(bh * 2048 + q0 + 32 + lane)) * SP + sp] = l1;
    }
}

// ---------------------------------------------------------------------------
// Combine SP K-split partials (plain sums; no max weights needed).
// ---------------------------------------------------------------------------
template<int SP>
__global__ void attn_combine(const float* __restrict__ Opart,
                             const float* __restrict__ lpart,
                             bf16* __restrict__ op) {
    const int gidx = blockIdx.x * 256 + threadIdx.x;  // 0..131071
    const int row  = gidx >> 2;                        // bh*2048 + q
    const int c0   = (gidx & 3) * 16;

    float acc[16];
    #pragma unroll
    for (int j = 0; j < 16; ++j) acc[j] = 0.f;
    float L = 0.f;
    #pragma unroll
    for (int s = 0; s < SP; ++s) {
        const float* src = Opart + ((size_t)row * SP + s) * 64 + c0;
        const float4 v0 = reinterpret_cast<const float4*>(src)[0];
        const float4 v1 = reinterpret_cast<const float4*>(src)[1];
        const float4 v2 = reinterpret_cast<const float4*>(src)[2];
        const float4 v3 = reinterpret_cast<const float4*>(src)[3];
        acc[0] += v0.x; acc[1] += v0.y; acc[2]  += v0.z; acc[3]  += v0.w;
        acc[4] += v1.x; acc[5] += v1.y; acc[6]  += v1.z; acc[7]  += v1.w;
        acc[8] += v2.x; acc[9] += v2.y; acc[10] += v2.z; acc[11] += v2.w;
        acc[12] += v3.x; acc[13] += v3.y; acc[14] += v3.z; acc[15] += v3.w;
        L += lpart[(size_t)row * SP + s];
    }
    const float invL = 1.0f / L;

    const int bh = row >> 11;
    const int q  = row & 2047;
    const int bb = bh >> 3;
    const int hh = bh & 7;
    bf16* dst = op + ((size_t)bb * 2048 + q) * 512 + hh * 64 + c0;
    bf16x8 r0, r1;
    #pragma unroll
    for (int j = 0; j < 8; ++j) {
        r0[j] = f2bf(acc[j] * invL);
        r1[j] = f2bf(acc[8 + j] * invL);
    }
    *reinterpret_cast<bf16x8*>(dst)     = r0;
    *reinterpret_cast<bf16x8*>(dst + 8) = r1;
}

// ---------------------------------------------------------------------------
extern "C" void kernel_launch(void* const* d_in, const int* in_sizes, int n_in,
                              void* d_out, int out_size, void* d_ws, size_t ws_size,
                              hipStream_t stream) {
    const float* q    = (const float*)d_in[0];
    const float* kv   = (const float*)d_in[1];
    const float* gate = (const float*)d_in[2];
    const int*   mask = (const int*)d_in[3];
    const float* Wq = (const float*)d_in[4];  const float* bq = (const float*)d_in[5];
    const float* Wk = (const float*)d_in[6];  const float* bk = (const float*)d_in[7];
    const float* Wv = (const float*)d_in[8];  const float* bv = (const float*)d_in[9];
    const float* Wo = (const float*)d_in[10]; const float* bo = (const float*)d_in[11];
    float* out = (float*)d_out;

    char* ws = (char*)d_ws;
    float* g2  = (float*)ws;
    bf16* Wqb  = (bf16*)(ws + (1u  << 20));
    bf16* Wkb  = (bf16*)(ws + (1u  << 20) + (512u << 10));
    bf16* Wvb  = (bf16*)(ws + (2u  << 20));
    bf16* Wob  = (bf16*)(ws + (2u  << 20) + (512u << 10));
    bf16* qb   = (bf16*)(ws + (3u  << 20));
    bf16* kvb  = (bf16*)(ws + (7u  << 20));
    bf16* qp   = (bf16*)(ws + (15u << 20));
    bf16* kf   = (bf16*)(ws + (19u << 20));
    bf16* vf   = (bf16*)(ws + (27u << 20));
    bf16* op   = (bf16*)(ws + (35u << 20));
    float* Opart = (float*)(ws + (39u << 20));
    float* lpart = (float*)(ws + (71u << 20));

    cvt_all<<<7176, 256, 0, stream>>>(q, kv, Wq, Wk, Wv, Wo, gate, mask,
                                      qb, kvb, Wqb, Wkb, Wvb, Wob, g2);

    proj_qkv<<<1280, 256, 0, stream>>>(qb, kvb, Wqb, bq, Wkb, bk,
                                       Wvb, bv, qp, kf, vf);

    attn_kernel<4><<<512, 256, 0, stream>>>(qp, kf, vf, g2, Opart, lpart);
    attn_combine<4><<<512, 256, 0, stream>>>(Opart, lpart, op);

    proj_o<<<256, 256, 0, stream>>>(op, Wob, bo, out);
}